// Round 9
// baseline (992.860 us; speedup 1.0000x reference)
//
#include <hip/hip_runtime.h>
#include <math.h>

#define NSAMP   32768
#define NFRAMES 128
#define NHARM   16
#define BATCH   64
#define MFFT    16384          // complex FFT size (even/odd real pack), = 128*128
#define ZROW    137            // LDS row stride (float2) per 128-entry FFT row
#define NWG     2048           // 8 WG/CU x 256 CU -- co-residency by capacity

static __device__ __forceinline__ float clampf(float x, float lo, float hi) {
  return fminf(fmaxf(x, lo), hi);
}
static __device__ __forceinline__ int zp(int fft, int p) {        // LDS swizzle
  return fft * ZROW + p + (p >> 4);
}
static __device__ __forceinline__ int brev7(int n) {
  return (int)(__brev((unsigned)n) >> 25);
}
static __device__ __forceinline__ float2 cmulf(float c, float s, float2 v) {
  return make_float2(c * v.x - s * v.y, c * v.y + s * v.x);
}
static __device__ __forceinline__ float2 f2add(float2 a, float2 b) {
  return make_float2(a.x + b.x, a.y + b.y);
}
static __device__ __forceinline__ float2 f2sub(float2 a, float2 b) {
  return make_float2(a.x - b.x, a.y - b.y);
}

// ---------------------------------------------------------------------------
// software grid barrier: monotonic counters zeroed by hipMemsetAsync per call.
// release: threadfence + device-scope add; acquire: spin + threadfence (L1 inv)
// ---------------------------------------------------------------------------
static __device__ __forceinline__ void gridbar(unsigned* ctr, int idx) {
  __syncthreads();
  if (threadIdx.x == 0) {
    __threadfence();
    __hip_atomic_fetch_add(&ctr[idx], 1u, __ATOMIC_RELEASE, __HIP_MEMORY_SCOPE_AGENT);
    while (__hip_atomic_load(&ctr[idx], __ATOMIC_ACQUIRE, __HIP_MEMORY_SCOPE_AGENT) < (unsigned)NWG)
      __builtin_amdgcn_s_sleep(2);
  }
  __syncthreads();
  __threadfence();
}

// ---------------------------------------------------------------------------
// 4 FFTs of length 128 in LDS, 128 threads, radix-4 fused stage-pairs
// (3 radix-4 + 1 radix-2). DIT: bit-reversed input -> natural output.
// tws[j] = e^{-i pi j/64}; INV conjugates; w2b = (fwd) -i*w2a / (inv) +i*w2a.
// ---------------------------------------------------------------------------
template <bool INV>
static __device__ __forceinline__ void fft128_r4(float2* zs, const float2* tws, int tid) {
  int fft = tid >> 5, i = tid & 31;
  #pragma unroll
  for (int s = 0; s < 6; s += 2) {
    int half = 1 << s;
    int kk1 = i & (half - 1);
    int base = ((i & ~(half - 1)) << 2) | kk1;
    int p0 = zp(fft, base),            p1 = zp(fft, base + half);
    int p2 = zp(fft, base + 2 * half), p3 = zp(fft, base + 3 * half);
    float2 q0 = zs[p0], q1 = zs[p1], q2 = zs[p2], q3 = zs[p3];
    float2 t1 = tws[kk1 << (6 - s)], t2 = tws[kk1 << (5 - s)];
    float c1 = t1.x, s1 = INV ? -t1.y : t1.y;
    float c2 = t2.x, s2 = INV ? -t2.y : t2.y;
    float c2b = INV ? -s2 : s2, s2b = INV ? c2 : -c2;
    float2 t;
    t = cmulf(c1, s1, q1);   float2 A0 = f2add(q0, t), A1 = f2sub(q0, t);
    t = cmulf(c1, s1, q3);   float2 A2 = f2add(q2, t), A3 = f2sub(q2, t);
    t = cmulf(c2, s2, A2);   zs[p0] = f2add(A0, t); zs[p2] = f2sub(A0, t);
    t = cmulf(c2b, s2b, A3); zs[p1] = f2add(A1, t); zs[p3] = f2sub(A1, t);
    __syncthreads();
  }
  #pragma unroll
  for (int j = tid; j < 256; j += 128) {           // stage 6, radix-2
    int f = j >> 6, kk = j & 63;
    float2 w = tws[kk];
    float cc = w.x, ss = INV ? -w.y : w.y;
    int a0 = zp(f, kk), a1 = zp(f, kk + 64);
    float2 a = zs[a0], bv = zs[a1];
    float2 t = cmulf(cc, ss, bv);
    zs[a0] = f2add(a, t); zs[a1] = f2sub(a, t);
  }
  __syncthreads();
}

// Inverse as DIF: natural input -> bit-reversed output. Stage 6 first, then
// fused pairs (5,4),(3,2),(1,0). Twiddles conjugated; w2b = +i*w2a.
static __device__ __forceinline__ void fft128_r4_dif_inv(float2* zs, const float2* tws, int tid) {
  #pragma unroll
  for (int j = tid; j < 256; j += 128) {           // stage 6, radix-2 DIF
    int f = j >> 6, kk = j & 63;
    float2 w = tws[kk];
    float cc = w.x, ss = -w.y;
    int a0 = zp(f, kk), a1 = zp(f, kk + 64);
    float2 u = zs[a0], v = zs[a1];
    zs[a0] = f2add(u, v);
    zs[a1] = cmulf(cc, ss, f2sub(u, v));
  }
  __syncthreads();
  int fft = tid >> 5, i = tid & 31;
  #pragma unroll
  for (int s = 4; s >= 0; s -= 2) {
    int half = 1 << s;
    int kk1 = i & (half - 1);
    int base = ((i & ~(half - 1)) << 2) | kk1;
    int p0 = zp(fft, base),            p1 = zp(fft, base + half);
    int p2 = zp(fft, base + 2 * half), p3 = zp(fft, base + 3 * half);
    float2 q0 = zs[p0], q1 = zs[p1], q2 = zs[p2], q3 = zs[p3];
    float2 t1 = tws[kk1 << (6 - s)], t2 = tws[kk1 << (5 - s)];
    float c1 = t1.x, s1 = -t1.y;
    float c2 = t2.x, s2 = -t2.y;
    float c2b = -s2, s2b = c2;                  // +i * (c2, s2)
    float2 B0 = f2add(q0, q2);
    float2 B2 = cmulf(c2, s2, f2sub(q0, q2));
    float2 B1 = f2add(q1, q3);
    float2 B3 = cmulf(c2b, s2b, f2sub(q1, q3));
    zs[p0] = f2add(B0, B1);
    zs[p1] = cmulf(c1, s1, f2sub(B0, B1));
    zs[p2] = f2add(B2, B3);
    zs[p3] = cmulf(c1, s1, f2sub(B2, B3));
    __syncthreads();
  }
}

static __device__ __forceinline__ float h_filter(int f, const float* nf_s) {
  float coords = ((float)f + 0.5f) * (1.0f / 256.0f) - 0.5f;
  coords = clampf(coords, 0.0f, 63.0f);
  int i0 = (int)coords;
  int i1 = (i0 < 63) ? (i0 + 1) : 63;
  float w = coords - (float)i0;
  return nf_s[i0] * (1.0f - w) + nf_s[i1] * w;
}

static __device__ __forceinline__ float amp_lerp(int s, const float* amp_s) {
  float coords = ((float)s + 0.5f) * (1.0f / 256.0f) - 0.5f;
  coords = clampf(coords, 0.0f, 127.0f);
  int i0 = (int)coords;
  int i1 = (i0 < 127) ? (i0 + 1) : 127;
  float w = coords - (float)i0;
  float v = amp_s[i0] * (1.0f - w) + amp_s[i1] * w;
  return clampf(v, 0.0f, 1.0f);
}

// ---------------------------------------------------------------------------
// k1 body (tile-0 WGs, phase A): gumbel argmax -> f0 -> radians (f64);
// 128-frame env scan. env layout: env_ws[frame*1024 + channel]
// ---------------------------------------------------------------------------
static __device__ void k1_body(
    const float* __restrict__ packed, const float* __restrict__ gumbel,
    double* __restrict__ r64_ws, float* __restrict__ env_ws, int b, int tid) {
  __shared__ double zv[128];
  __shared__ int    zi[128];
  __shared__ double f0_sh;
  const float* pk = packed + b * 480;

  double u = (double)gumbel[b * 128 + tid];
  double t = -log(u + 1e-10);
  double g = -log(t + 1e-10);
  zv[tid] = (double)pk[tid] + g;
  zi[tid] = tid;
  __syncthreads();
  for (int s = 64; s > 0; s >>= 1) {
    if (tid < s) {
      double a = zv[tid], c = zv[tid + s];
      int ia = zi[tid], ic = zi[tid + s];
      if (c > a || (c == a && ic < ia)) { zv[tid] = c; zi[tid] = ic; }
    }
    __syncthreads();
  }
  if (tid == 0) {
    int note = zi[0];
    double Fd  = 440.0 * exp2(((double)(note - 69)) / 12.0) / 11025.0;
    float  F32 = (float)Fd;                     // FREQS is f32 in the reference
    double f0  = (double)F32 * 11025.0;
    f0 = (40.0 / 11025.0) + f0 * (3000.0 / 11025.0 - 40.0 / 11025.0);
    f0_sh = f0;
  }
  __syncthreads();
  if (tid < NHARM) {
    int h = tid;
    int c = b * NHARM + h;
    const float PIF = 3.14159265358979323846f;  // float32(np.pi)
    double osc = f0_sh * (double)(h + 1);
    r64_ws[c] = (osc / 11025.0) * (double)PIF;
    float ha = pk[384 + h];
    float hd = 0.1f + pk[400 + h] * 0.9f;
    float cur = 0.0f;
    for (int tt = 0; tt < NFRAMES; ++tt) {
      float a = pk[256 + tt] * 2.0f - 1.0f;
      cur = clampf(cur + a * ha, 0.0f, 1.0f);
      env_ws[tt * 1024 + c] = cur;
      cur = cur * hd;
    }
  }
  __syncthreads();
}

// ---------------------------------------------------------------------------
// phase A: column FFTs (length 128 over n1) + W_M^{n2 k1} twiddle
// ---------------------------------------------------------------------------
static __device__ void kf1_body(
    float2* zs, const float2* tws, const float* __restrict__ noise_u,
    float2* __restrict__ A, int b, int tile, int tid) {
  const float2* nu2 = (const float2*)(noise_u + (size_t)b * NSAMP);
  #pragma unroll
  for (int it = 0; it < 4; ++it) {
    int e = it * 128 + tid;
    int n1 = e >> 2, n2l = e & 3;
    float2 xv = nu2[n1 * 128 + tile * 4 + n2l];
    zs[zp(n2l, brev7(n1))] = make_float2(xv.x * 2.0f - 1.0f, xv.y * 2.0f - 1.0f);
  }
  __syncthreads();
  fft128_r4<false>(zs, tws, tid);
  float2* Ab = A + (size_t)b * MFFT;
  #pragma unroll
  for (int it = 0; it < 4; ++it) {
    int e = it * 128 + tid;
    int k1 = e >> 2, n2l = e & 3;
    int n2 = tile * 4 + n2l;
    float2 v = zs[zp(n2l, k1)];
    float ang = -(2.0f * (float)M_PI / 16384.0f) * (float)(k1 * n2);
    float ss, cc; __sincosf(ang, &ss, &cc);
    Ab[k1 * 128 + n2] = make_float2(cc * v.x - ss * v.y, cc * v.y + ss * v.x);
  }
}

// ---------------------------------------------------------------------------
// phase B: fused row-FFT (fwd) -> Hermitian filter (LDS) -> row-IFFT (DIF)
//          -> conj twiddle. 4 rows = 2 pair-groups per WG.
// ---------------------------------------------------------------------------
static __device__ void kmid_body(
    float2* zs, const float2* tws, const float* __restrict__ packed,
    float2* __restrict__ A, int b, int t, int tid) {
  __shared__ float nf_s[64];
  __shared__ int   rowk1[4];
  if (tid >= 64 && tid < 128) nf_s[tid - 64] = packed[b * 480 + 416 + (tid - 64)];
  if (tid < 4) {
    int s = tid & 1;
    int m = t * 2 + s;
    rowk1[tid] = (tid < 2) ? m : ((m == 0) ? 64 : 128 - m);
  }
  __syncthreads();
  float2* Ab = A + (size_t)b * MFFT;

  #pragma unroll
  for (int it = 0; it < 4; ++it) {
    int e = it * 128 + tid;
    int r = e >> 7, n2 = e & 127;
    zs[zp(r, brev7(n2))] = Ab[rowk1[r] * 128 + n2];
  }
  __syncthreads();
  fft128_r4<false>(zs, tws, tid);   // zs[zp(r,k2)] = Z[rowk1[r] + 128*k2]

  const float hsc = 1.0f / 16384.0f;
  #pragma unroll
  for (int it = 0; it < 2; ++it) {
    int task = it * 128 + tid;      // 256 tasks: (local row r, k2 in 0..63)
    int r  = task >> 6;
    int k2 = task & 63;
    int k1 = rowk1[r];
    int f = k1 + (k2 << 7);
    if (f == 0) {                   // DC and f=8192 specials (WG t=0 only)
      float2 Z0 = zs[zp(0, 0)];
      float X0 = Z0.x + Z0.y;
      float Y0 = X0 * (h_filter(0, nf_s) * hsc);
      zs[zp(0, 0)] = make_float2(0.5f * Y0, 0.5f * Y0);   // H[M]=0 -> YM=0
      float Hm = h_filter(8192, nf_s) * hsc;
      float2 Zm = zs[zp(0, 64)];
      zs[zp(0, 64)] = make_float2(Zm.x * Hm, Zm.y * Hm);
    } else {
      int g = 16384 - f;
      int k1g = g & 127;
      int pr = (k1g == k1) ? r : ((r < 2) ? r + 2 : r - 2);
      int k2p = g >> 7;
      float2 Zf = zs[zp(r, k2)], Zg = zs[zp(pr, k2p)];
      float Ax = 0.5f * (Zf.x + Zg.x), Ay = 0.5f * (Zf.y - Zg.y);
      float Bx = 0.5f * (Zf.x - Zg.x), By = 0.5f * (Zf.y + Zg.y);
      float ang = (-(float)M_PI / (float)MFFT) * (float)f;
      float ss, cc; __sincosf(ang, &ss, &cc);
      float WBx = cc * Bx - ss * By, WBy = cc * By + ss * Bx;
      float Hf = h_filter(f, nf_s) * hsc;
      float Hg = h_filter(g, nf_s) * hsc;
      float Yfx = (Ax + WBy) * Hf, Yfy = (Ay - WBx) * Hf;
      float Ygx = (Ax - WBy) * Hg, Ygy = (-Ay - WBx) * Hg;
      float A2x = 0.5f * (Yfx + Ygx), A2y = 0.5f * (Yfy - Ygy);
      float B2x = 0.5f * (Yfx - Ygx), B2y = 0.5f * (Yfy + Ygy);
      float CBx = cc * B2x + ss * B2y;
      float CBy = cc * B2y - ss * B2x;
      zs[zp(r, k2)]   = make_float2(A2x - CBy, A2y + CBx);
      float DBx = cc * B2x + ss * B2y;
      float DBy = ss * B2x - cc * B2y;
      zs[zp(pr, k2p)] = make_float2(A2x - DBy, -A2y + DBx);
    }
  }
  __syncthreads();

  fft128_r4_dif_inv(zs, tws, tid);  // natural -> bitrev

  #pragma unroll
  for (int it = 0; it < 4; ++it) {
    int e = it * 128 + tid;
    int r = e >> 7, n2 = e & 127;
    int k1 = rowk1[r];
    float2 v = zs[zp(r, brev7(n2))];
    float ang = (2.0f * (float)M_PI / 16384.0f) * (float)(k1 * n2);
    float ss, cc; __sincosf(ang, &ss, &cc);
    Ab[k1 * 128 + n2] = make_float2(cc * v.x - ss * v.y, cc * v.y + ss * v.x);
  }
}

// ---------------------------------------------------------------------------
// phase C: column inverse FFTs (over k1) + amp*clip -> ws2
// ---------------------------------------------------------------------------
static __device__ void ki2_body(
    float2* zs, const float2* tws, const float* __restrict__ packed,
    const float2* __restrict__ A, float2* __restrict__ ws2, int b, int tile, int tid) {
  __shared__ float amp_s[128];
  amp_s[tid] = packed[b * 480 + 256 + tid] * 2.0f - 1.0f;
  const float2* Ab = A + (size_t)b * MFFT;
  #pragma unroll
  for (int it = 0; it < 4; ++it) {
    int e = it * 128 + tid;
    int k1 = e >> 2, n2l = e & 3;
    zs[zp(n2l, brev7(k1))] = Ab[k1 * 128 + tile * 4 + n2l];
  }
  __syncthreads();
  fft128_r4<true>(zs, tws, tid);
  float2* W2 = ws2 + (size_t)b * MFFT;
  #pragma unroll
  for (int it = 0; it < 4; ++it) {
    int e = it * 128 + tid;
    int n1 = e >> 2, n2l = e & 3;
    int n2 = tile * 4 + n2l;
    int n = n1 * 128 + n2;
    float2 v = zs[zp(n2l, n1)];
    v.x *= amp_lerp(2 * n,     amp_s);
    v.y *= amp_lerp(2 * n + 1, amp_s);
    W2[n] = v;
  }
}

// ---------------------------------------------------------------------------
// phase D: oscillator bank (Chebyshev harmonic recurrence) + batch-mean of
// noise. wg = chunk*8 + sub; WG covers 16 samples; wave lane = batch.
// ---------------------------------------------------------------------------
static __device__ void k3r_body(
    const double* __restrict__ r64_ws, const float* __restrict__ env_ws,
    const float* __restrict__ ws2f, float* __restrict__ out, int wg, int tid) {
  __shared__ float nse[8][16];
  __shared__ float oscs[16];
  const double TWO_PI     = 6.283185307179586476925286766559;
  const double INV_TWO_PI = 0.15915494309189533576888376337251;
  int lane = tid & 63;               // batch
  int w = tid >> 6;                  // wave: 8 samples each
  int chunk = wg >> 3, sub = wg & 7;
  int s0 = chunk * 128 + sub * 16;
  int K = chunk >> 1, half = chunk & 1;

  double r0 = r64_ws[lane * 16];     // fundamental step angle (f64)
  double rr = r0 - rint(r0 * INV_TWO_PI) * TWO_PI;
  double x0 = (double)(s0 + w * 8 + 1) * r0;
  double ph = x0 - rint(x0 * INV_TWO_PI) * TWO_PI;
  float s1, c1, srot, crot;
  __sincosf((float)ph, &s1, &c1);
  __sincosf((float)rr, &srot, &crot);

  int km1 = (K > 0) ? (K - 1) : 0;
  int kp1 = (K < 127) ? (K + 1) : 127;
  int fA = half ? K : km1;
  int fB = half ? kp1 : K;
  const float4* eA = (const float4*)(env_ws + fA * 1024 + lane * 16);
  const float4* eB = (const float4*)(env_ws + fB * 1024 + lane * 16);
  float ev[16], sl[16];
  float basew = (half ? 0.5f : 128.5f) + (float)(sub * 16 + w * 8);
  #pragma unroll
  for (int q = 0; q < 4; ++q) {
    float4 a = eA[q], bb = eB[q];
    float d;
    d = (bb.x - a.x) * (1.0f / 256.0f); sl[q*4+0] = d; ev[q*4+0] = a.x + d * basew;
    d = (bb.y - a.y) * (1.0f / 256.0f); sl[q*4+1] = d; ev[q*4+1] = a.y + d * basew;
    d = (bb.z - a.z) * (1.0f / 256.0f); sl[q*4+2] = d; ev[q*4+2] = a.z + d * basew;
    d = (bb.w - a.w) * (1.0f / 256.0f); sl[q*4+3] = d; ev[q*4+3] = a.w + d * basew;
  }

  #pragma unroll
  for (int j = 0; j < 8; ++j) {
    float twoC = c1 + c1;
    float sm1 = 0.0f, sc = s1;
    float acc = ev[0] * sc; ev[0] += sl[0];
    #pragma unroll
    for (int i = 1; i < 16; ++i) {
      float sn = fmaf(twoC, sc, -sm1);
      sm1 = sc; sc = sn;
      acc = fmaf(ev[i], sn, acc);
      ev[i] += sl[i];
    }
    acc += __shfl_xor(acc, 32);
    acc += __shfl_xor(acc, 16);
    acc += __shfl_xor(acc, 8);
    acc += __shfl_xor(acc, 4);
    acc += __shfl_xor(acc, 2);
    acc += __shfl_xor(acc, 1);
    if (lane == 0) oscs[w * 8 + j] = acc;
    float tn = fmaf(s1, crot, c1 * srot);      // uses old s1,c1
    c1 = fmaf(c1, crot, -(s1 * srot));
    s1 = tn;
  }
  __syncthreads();

  // batch-mean of noise: 8 groups x 8 batches, 16 samples
  {
    int j = tid & 15, grp = tid >> 4;
    const float* src = ws2f + (size_t)(grp * 8) * NSAMP + s0 + j;
    float acc = 0.0f;
    #pragma unroll
    for (int bb = 0; bb < 8; ++bb) acc += src[(size_t)bb * NSAMP];
    nse[grp][j] = acc;
  }
  __syncthreads();

  if (tid < 16) {
    float nz = 0.0f;
    #pragma unroll
    for (int g = 0; g < 8; ++g) nz += nse[g][tid];
    out[s0 + tid] = oscs[tid] * (1.0f / 1024.0f) + nz * (1.0f / 64.0f);
  }
}

// ---------------------------------------------------------------------------
// the fused whole-pipeline kernel: A | bar | B | bar | C | bar | D
// ---------------------------------------------------------------------------
__global__ __launch_bounds__(128, 4) void kcoop(
    const float* __restrict__ noise_u, float2* __restrict__ A,
    float2* __restrict__ ws2, const float* __restrict__ packed,
    const float* __restrict__ gumbel, double* __restrict__ r64_ws,
    float* __restrict__ env_ws, float* __restrict__ out, unsigned* ctr) {
  __shared__ float2 zs[4 * ZROW];
  __shared__ float2 tws[64];
  int wg = blockIdx.x, tid = threadIdx.x;
  int b = wg >> 5, t = wg & 31;

  if (tid < 64) {
    float s, c;
    __sincosf(-(float)M_PI * (float)tid * (1.0f / 64.0f), &s, &c);
    tws[tid] = make_float2(c, s);
  }
  // phase A (tile-0 WGs also run the tiny per-batch setup first)
  if (t == 0) k1_body(packed, gumbel, r64_ws, env_ws, b, tid);
  kf1_body(zs, tws, noise_u, A, b, t, tid);
  gridbar(ctr, 0);
  kmid_body(zs, tws, packed, A, b, t, tid);
  gridbar(ctr, 1);
  ki2_body(zs, tws, packed, A, ws2, b, t, tid);
  gridbar(ctr, 2);
  k3r_body(r64_ws, env_ws, (const float*)ws2, out, wg, tid);
}

// ---------------------------------------------------------------------------
extern "C" void kernel_launch(void* const* d_in, const int* in_sizes, int n_in,
                              void* d_out, int out_size, void* d_ws, size_t ws_size,
                              hipStream_t stream) {
  const float* packed  = (const float*)d_in[0];
  const float* gumbel  = (const float*)d_in[1];
  const float* noise_u = (const float*)d_in[2];
  float* out = (float*)d_out;

  // ws layout: [r64 8KB][env 512KB][A 8MB][ws2 8MB] ... [ctr @48MB]
  char* wsc = (char*)d_ws;
  double*   r64_ws = (double*)wsc;
  float*    env_ws = (float*)(wsc + 8192);
  float2*   A      = (float2*)(wsc + 8192 + 524288);
  float2*   ws2    = (float2*)(wsc + 8192 + 524288 + (size_t)BATCH * MFFT * 8);
  unsigned* ctr    = (unsigned*)(wsc + (size_t)48 * 1024 * 1024);

  hipMemsetAsync(ctr, 0, 64, stream);
  kcoop<<<NWG, 128, 0, stream>>>(noise_u, A, ws2, packed, gumbel,
                                 r64_ws, env_ws, out, ctr);
}

// Round 10
// 713.515 us; speedup vs baseline: 1.3915x; 1.3915x over previous
//
#include <hip/hip_runtime.h>
#include <math.h>

#define NSAMP   32768
#define NFRAMES 128
#define NHARM   16
#define BATCH   64
#define MFFT    16384          // complex FFT size (even/odd real pack), = 128*128
#define ZROW    137            // LDS row stride (float2) per 128-entry FFT row
#define NWG     2048           // 8 WG/CU x 256 CU -- co-residency by capacity

static __device__ __forceinline__ float clampf(float x, float lo, float hi) {
  return fminf(fmaxf(x, lo), hi);
}
static __device__ __forceinline__ int zp(int fft, int p) {        // LDS swizzle
  return fft * ZROW + p + (p >> 4);
}
static __device__ __forceinline__ int brev7(int n) {
  return (int)(__brev((unsigned)n) >> 25);
}
static __device__ __forceinline__ float2 cmulf(float c, float s, float2 v) {
  return make_float2(c * v.x - s * v.y, c * v.y + s * v.x);
}
static __device__ __forceinline__ float2 f2add(float2 a, float2 b) {
  return make_float2(a.x + b.x, a.y + b.y);
}
static __device__ __forceinline__ float2 f2sub(float2 a, float2 b) {
  return make_float2(a.x - b.x, a.y - b.y);
}

// ---------------------------------------------------------------------------
// Barriers. Counter block layout (uint stride 32 = 128B lines):
//   ctr[(p*64+b)*32]  p=0,1,2 : per-batch arrival counters (32 WGs each)
//   gflag = ctr + GOFF        : global batch-completion count (64 writers)
//   rls[b*32] = ctr + ROFF    : per-batch release flags for the global bar
// All zeroed by hipMemsetAsync each call (monotonic within a call).
// ---------------------------------------------------------------------------
#define GOFF  (3 * 64 * 32)
#define ROFF  (GOFF + 32)

static __device__ __forceinline__ void batchbar(unsigned* ctr, int p, int b) {
  __syncthreads();
  if (threadIdx.x == 0) {
    __threadfence();
    unsigned* a = ctr + (p * 64 + b) * 32;
    __hip_atomic_fetch_add(a, 1u, __ATOMIC_ACQ_REL, __HIP_MEMORY_SCOPE_AGENT);
    while (__hip_atomic_load(a, __ATOMIC_ACQUIRE, __HIP_MEMORY_SCOPE_AGENT) < 32u)
      __builtin_amdgcn_s_sleep(1);
  }
  __syncthreads();
  __threadfence();
}

static __device__ __forceinline__ void globalbar(unsigned* ctr, int p, int b) {
  __syncthreads();
  if (threadIdx.x == 0) {
    __threadfence();
    unsigned* a = ctr + (p * 64 + b) * 32;
    unsigned* gflag = ctr + GOFF;
    unsigned* rls = ctr + ROFF + b * 32;
    unsigned old = __hip_atomic_fetch_add(a, 1u, __ATOMIC_ACQ_REL, __HIP_MEMORY_SCOPE_AGENT);
    if (old == 31u) {                    // last WG of this batch
      __hip_atomic_fetch_add(gflag, 1u, __ATOMIC_ACQ_REL, __HIP_MEMORY_SCOPE_AGENT);
      while (__hip_atomic_load(gflag, __ATOMIC_ACQUIRE, __HIP_MEMORY_SCOPE_AGENT) < 64u)
        __builtin_amdgcn_s_sleep(2);
      __hip_atomic_store(rls, 1u, __ATOMIC_RELEASE, __HIP_MEMORY_SCOPE_AGENT);
    }
    while (__hip_atomic_load(rls, __ATOMIC_ACQUIRE, __HIP_MEMORY_SCOPE_AGENT) == 0u)
      __builtin_amdgcn_s_sleep(1);
  }
  __syncthreads();
  __threadfence();
}

// ---------------------------------------------------------------------------
// 4 FFTs of length 128 in LDS, 128 threads, radix-4 fused stage-pairs
// (3 radix-4 + 1 radix-2). DIT: bit-reversed input -> natural output.
// tws[j] = e^{-i pi j/64}; INV conjugates; w2b = (fwd) -i*w2a / (inv) +i*w2a.
// ---------------------------------------------------------------------------
template <bool INV>
static __device__ __forceinline__ void fft128_r4(float2* zs, const float2* tws, int tid) {
  int fft = tid >> 5, i = tid & 31;
  #pragma unroll
  for (int s = 0; s < 6; s += 2) {
    int half = 1 << s;
    int kk1 = i & (half - 1);
    int base = ((i & ~(half - 1)) << 2) | kk1;
    int p0 = zp(fft, base),            p1 = zp(fft, base + half);
    int p2 = zp(fft, base + 2 * half), p3 = zp(fft, base + 3 * half);
    float2 q0 = zs[p0], q1 = zs[p1], q2 = zs[p2], q3 = zs[p3];
    float2 t1 = tws[kk1 << (6 - s)], t2 = tws[kk1 << (5 - s)];
    float c1 = t1.x, s1 = INV ? -t1.y : t1.y;
    float c2 = t2.x, s2 = INV ? -t2.y : t2.y;
    float c2b = INV ? -s2 : s2, s2b = INV ? c2 : -c2;
    float2 t;
    t = cmulf(c1, s1, q1);   float2 A0 = f2add(q0, t), A1 = f2sub(q0, t);
    t = cmulf(c1, s1, q3);   float2 A2 = f2add(q2, t), A3 = f2sub(q2, t);
    t = cmulf(c2, s2, A2);   zs[p0] = f2add(A0, t); zs[p2] = f2sub(A0, t);
    t = cmulf(c2b, s2b, A3); zs[p1] = f2add(A1, t); zs[p3] = f2sub(A1, t);
    __syncthreads();
  }
  #pragma unroll
  for (int j = tid; j < 256; j += 128) {           // stage 6, radix-2
    int f = j >> 6, kk = j & 63;
    float2 w = tws[kk];
    float cc = w.x, ss = INV ? -w.y : w.y;
    int a0 = zp(f, kk), a1 = zp(f, kk + 64);
    float2 a = zs[a0], bv = zs[a1];
    float2 t = cmulf(cc, ss, bv);
    zs[a0] = f2add(a, t); zs[a1] = f2sub(a, t);
  }
  __syncthreads();
}

// Inverse as DIF: natural input -> bit-reversed output. Stage 6 first, then
// fused pairs (5,4),(3,2),(1,0). Twiddles conjugated; w2b = +i*w2a.
static __device__ __forceinline__ void fft128_r4_dif_inv(float2* zs, const float2* tws, int tid) {
  #pragma unroll
  for (int j = tid; j < 256; j += 128) {           // stage 6, radix-2 DIF
    int f = j >> 6, kk = j & 63;
    float2 w = tws[kk];
    float cc = w.x, ss = -w.y;
    int a0 = zp(f, kk), a1 = zp(f, kk + 64);
    float2 u = zs[a0], v = zs[a1];
    zs[a0] = f2add(u, v);
    zs[a1] = cmulf(cc, ss, f2sub(u, v));
  }
  __syncthreads();
  int fft = tid >> 5, i = tid & 31;
  #pragma unroll
  for (int s = 4; s >= 0; s -= 2) {
    int half = 1 << s;
    int kk1 = i & (half - 1);
    int base = ((i & ~(half - 1)) << 2) | kk1;
    int p0 = zp(fft, base),            p1 = zp(fft, base + half);
    int p2 = zp(fft, base + 2 * half), p3 = zp(fft, base + 3 * half);
    float2 q0 = zs[p0], q1 = zs[p1], q2 = zs[p2], q3 = zs[p3];
    float2 t1 = tws[kk1 << (6 - s)], t2 = tws[kk1 << (5 - s)];
    float c1 = t1.x, s1 = -t1.y;
    float c2 = t2.x, s2 = -t2.y;
    float c2b = -s2, s2b = c2;                  // +i * (c2, s2)
    float2 B0 = f2add(q0, q2);
    float2 B2 = cmulf(c2, s2, f2sub(q0, q2));
    float2 B1 = f2add(q1, q3);
    float2 B3 = cmulf(c2b, s2b, f2sub(q1, q3));
    zs[p0] = f2add(B0, B1);
    zs[p1] = cmulf(c1, s1, f2sub(B0, B1));
    zs[p2] = f2add(B2, B3);
    zs[p3] = cmulf(c1, s1, f2sub(B2, B3));
    __syncthreads();
  }
}

static __device__ __forceinline__ float h_filter(int f, const float* nf_s) {
  float coords = ((float)f + 0.5f) * (1.0f / 256.0f) - 0.5f;
  coords = clampf(coords, 0.0f, 63.0f);
  int i0 = (int)coords;
  int i1 = (i0 < 63) ? (i0 + 1) : 63;
  float w = coords - (float)i0;
  return nf_s[i0] * (1.0f - w) + nf_s[i1] * w;
}

static __device__ __forceinline__ float amp_lerp(int s, const float* amp_s) {
  float coords = ((float)s + 0.5f) * (1.0f / 256.0f) - 0.5f;
  coords = clampf(coords, 0.0f, 127.0f);
  int i0 = (int)coords;
  int i1 = (i0 < 127) ? (i0 + 1) : 127;
  float w = coords - (float)i0;
  float v = amp_s[i0] * (1.0f - w) + amp_s[i1] * w;
  return clampf(v, 0.0f, 1.0f);
}

// ---------------------------------------------------------------------------
// k1 body (t==0 WGs, phase A): gumbel argmax -> f0 -> radians (f64);
// 128-frame env scan. env layout: env_ws[frame*1024 + channel]
// ---------------------------------------------------------------------------
static __device__ void k1_body(
    const float* __restrict__ packed, const float* __restrict__ gumbel,
    double* __restrict__ r64_ws, float* __restrict__ env_ws, int b, int tid) {
  __shared__ double zv[128];
  __shared__ int    zi[128];
  __shared__ double f0_sh;
  const float* pk = packed + b * 480;

  double u = (double)gumbel[b * 128 + tid];
  double t = -log(u + 1e-10);
  double g = -log(t + 1e-10);
  zv[tid] = (double)pk[tid] + g;
  zi[tid] = tid;
  __syncthreads();
  for (int s = 64; s > 0; s >>= 1) {
    if (tid < s) {
      double a = zv[tid], c = zv[tid + s];
      int ia = zi[tid], ic = zi[tid + s];
      if (c > a || (c == a && ic < ia)) { zv[tid] = c; zi[tid] = ic; }
    }
    __syncthreads();
  }
  if (tid == 0) {
    int note = zi[0];
    double Fd  = 440.0 * exp2(((double)(note - 69)) / 12.0) / 11025.0;
    float  F32 = (float)Fd;                     // FREQS is f32 in the reference
    double f0  = (double)F32 * 11025.0;
    f0 = (40.0 / 11025.0) + f0 * (3000.0 / 11025.0 - 40.0 / 11025.0);
    f0_sh = f0;
  }
  __syncthreads();
  if (tid < NHARM) {
    int h = tid;
    int c = b * NHARM + h;
    const float PIF = 3.14159265358979323846f;  // float32(np.pi)
    double osc = f0_sh * (double)(h + 1);
    r64_ws[c] = (osc / 11025.0) * (double)PIF;
    float ha = pk[384 + h];
    float hd = 0.1f + pk[400 + h] * 0.9f;
    float cur = 0.0f;
    for (int tt = 0; tt < NFRAMES; ++tt) {
      float a = pk[256 + tt] * 2.0f - 1.0f;
      cur = clampf(cur + a * ha, 0.0f, 1.0f);
      env_ws[tt * 1024 + c] = cur;
      cur = cur * hd;
    }
  }
  __syncthreads();
}

// ---------------------------------------------------------------------------
// phase A: column FFTs (length 128 over n1) + W_M^{n2 k1} twiddle
// ---------------------------------------------------------------------------
static __device__ void kf1_body(
    float2* zs, const float2* tws, const float* __restrict__ noise_u,
    float2* __restrict__ A, int b, int tile, int tid) {
  const float2* nu2 = (const float2*)(noise_u + (size_t)b * NSAMP);
  #pragma unroll
  for (int it = 0; it < 4; ++it) {
    int e = it * 128 + tid;
    int n1 = e >> 2, n2l = e & 3;
    float2 xv = nu2[n1 * 128 + tile * 4 + n2l];
    zs[zp(n2l, brev7(n1))] = make_float2(xv.x * 2.0f - 1.0f, xv.y * 2.0f - 1.0f);
  }
  __syncthreads();
  fft128_r4<false>(zs, tws, tid);
  float2* Ab = A + (size_t)b * MFFT;
  #pragma unroll
  for (int it = 0; it < 4; ++it) {
    int e = it * 128 + tid;
    int k1 = e >> 2, n2l = e & 3;
    int n2 = tile * 4 + n2l;
    float2 v = zs[zp(n2l, k1)];
    float ang = -(2.0f * (float)M_PI / 16384.0f) * (float)(k1 * n2);
    float ss, cc; __sincosf(ang, &ss, &cc);
    Ab[k1 * 128 + n2] = make_float2(cc * v.x - ss * v.y, cc * v.y + ss * v.x);
  }
}

// ---------------------------------------------------------------------------
// phase B: fused row-FFT (fwd) -> Hermitian filter (LDS) -> row-IFFT (DIF)
//          -> conj twiddle. 4 rows = 2 pair-groups per WG.
// ---------------------------------------------------------------------------
static __device__ void kmid_body(
    float2* zs, const float2* tws, const float* __restrict__ packed,
    float2* __restrict__ A, int b, int t, int tid) {
  __shared__ float nf_s[64];
  __shared__ int   rowk1[4];
  if (tid >= 64 && tid < 128) nf_s[tid - 64] = packed[b * 480 + 416 + (tid - 64)];
  if (tid < 4) {
    int s = tid & 1;
    int m = t * 2 + s;
    rowk1[tid] = (tid < 2) ? m : ((m == 0) ? 64 : 128 - m);
  }
  __syncthreads();
  float2* Ab = A + (size_t)b * MFFT;

  #pragma unroll
  for (int it = 0; it < 4; ++it) {
    int e = it * 128 + tid;
    int r = e >> 7, n2 = e & 127;
    zs[zp(r, brev7(n2))] = Ab[rowk1[r] * 128 + n2];
  }
  __syncthreads();
  fft128_r4<false>(zs, tws, tid);   // zs[zp(r,k2)] = Z[rowk1[r] + 128*k2]

  const float hsc = 1.0f / 16384.0f;
  #pragma unroll
  for (int it = 0; it < 2; ++it) {
    int task = it * 128 + tid;      // 256 tasks: (local row r, k2 in 0..63)
    int r  = task >> 6;
    int k2 = task & 63;
    int k1 = rowk1[r];
    int f = k1 + (k2 << 7);
    if (f == 0) {                   // DC and f=8192 specials (WG t=0 only)
      float2 Z0 = zs[zp(0, 0)];
      float X0 = Z0.x + Z0.y;
      float Y0 = X0 * (h_filter(0, nf_s) * hsc);
      zs[zp(0, 0)] = make_float2(0.5f * Y0, 0.5f * Y0);   // H[M]=0 -> YM=0
      float Hm = h_filter(8192, nf_s) * hsc;
      float2 Zm = zs[zp(0, 64)];
      zs[zp(0, 64)] = make_float2(Zm.x * Hm, Zm.y * Hm);
    } else {
      int g = 16384 - f;
      int k1g = g & 127;
      int pr = (k1g == k1) ? r : ((r < 2) ? r + 2 : r - 2);
      int k2p = g >> 7;
      float2 Zf = zs[zp(r, k2)], Zg = zs[zp(pr, k2p)];
      float Ax = 0.5f * (Zf.x + Zg.x), Ay = 0.5f * (Zf.y - Zg.y);
      float Bx = 0.5f * (Zf.x - Zg.x), By = 0.5f * (Zf.y + Zg.y);
      float ang = (-(float)M_PI / (float)MFFT) * (float)f;
      float ss, cc; __sincosf(ang, &ss, &cc);
      float WBx = cc * Bx - ss * By, WBy = cc * By + ss * Bx;
      float Hf = h_filter(f, nf_s) * hsc;
      float Hg = h_filter(g, nf_s) * hsc;
      float Yfx = (Ax + WBy) * Hf, Yfy = (Ay - WBx) * Hf;
      float Ygx = (Ax - WBy) * Hg, Ygy = (-Ay - WBx) * Hg;
      float A2x = 0.5f * (Yfx + Ygx), A2y = 0.5f * (Yfy - Ygy);
      float B2x = 0.5f * (Yfx - Ygx), B2y = 0.5f * (Yfy + Ygy);
      float CBx = cc * B2x + ss * B2y;
      float CBy = cc * B2y - ss * B2x;
      zs[zp(r, k2)]   = make_float2(A2x - CBy, A2y + CBx);
      float DBx = cc * B2x + ss * B2y;
      float DBy = ss * B2x - cc * B2y;
      zs[zp(pr, k2p)] = make_float2(A2x - DBy, -A2y + DBx);
    }
  }
  __syncthreads();

  fft128_r4_dif_inv(zs, tws, tid);  // natural -> bitrev

  #pragma unroll
  for (int it = 0; it < 4; ++it) {
    int e = it * 128 + tid;
    int r = e >> 7, n2 = e & 127;
    int k1 = rowk1[r];
    float2 v = zs[zp(r, brev7(n2))];
    float ang = (2.0f * (float)M_PI / 16384.0f) * (float)(k1 * n2);
    float ss, cc; __sincosf(ang, &ss, &cc);
    Ab[k1 * 128 + n2] = make_float2(cc * v.x - ss * v.y, cc * v.y + ss * v.x);
  }
}

// ---------------------------------------------------------------------------
// phase C: column inverse FFTs (over k1) + amp*clip -> ws2
// ---------------------------------------------------------------------------
static __device__ void ki2_body(
    float2* zs, const float2* tws, const float* __restrict__ packed,
    const float2* __restrict__ A, float2* __restrict__ ws2, int b, int tile, int tid) {
  __shared__ float amp_s[128];
  amp_s[tid] = packed[b * 480 + 256 + tid] * 2.0f - 1.0f;
  const float2* Ab = A + (size_t)b * MFFT;
  #pragma unroll
  for (int it = 0; it < 4; ++it) {
    int e = it * 128 + tid;
    int k1 = e >> 2, n2l = e & 3;
    zs[zp(n2l, brev7(k1))] = Ab[k1 * 128 + tile * 4 + n2l];
  }
  __syncthreads();
  fft128_r4<true>(zs, tws, tid);
  float2* W2 = ws2 + (size_t)b * MFFT;
  #pragma unroll
  for (int it = 0; it < 4; ++it) {
    int e = it * 128 + tid;
    int n1 = e >> 2, n2l = e & 3;
    int n2 = tile * 4 + n2l;
    int n = n1 * 128 + n2;
    float2 v = zs[zp(n2l, n1)];
    v.x *= amp_lerp(2 * n,     amp_s);
    v.y *= amp_lerp(2 * n + 1, amp_s);
    W2[n] = v;
  }
}

// ---------------------------------------------------------------------------
// phase D: oscillator bank (Chebyshev harmonic recurrence) + batch-mean of
// noise. wg = chunk*8 + sub; WG covers 16 samples; wave lane = batch.
// ---------------------------------------------------------------------------
static __device__ void k3r_body(
    const double* __restrict__ r64_ws, const float* __restrict__ env_ws,
    const float* __restrict__ ws2f, float* __restrict__ out, int wg, int tid) {
  __shared__ float nse[8][16];
  __shared__ float oscs[16];
  const double TWO_PI     = 6.283185307179586476925286766559;
  const double INV_TWO_PI = 0.15915494309189533576888376337251;
  int lane = tid & 63;               // batch
  int w = tid >> 6;                  // wave: 8 samples each
  int chunk = wg >> 3, sub = wg & 7;
  int s0 = chunk * 128 + sub * 16;
  int K = chunk >> 1, half = chunk & 1;

  double r0 = r64_ws[lane * 16];     // fundamental step angle (f64)
  double rr = r0 - rint(r0 * INV_TWO_PI) * TWO_PI;
  double x0 = (double)(s0 + w * 8 + 1) * r0;
  double ph = x0 - rint(x0 * INV_TWO_PI) * TWO_PI;
  float s1, c1, srot, crot;
  __sincosf((float)ph, &s1, &c1);
  __sincosf((float)rr, &srot, &crot);

  int km1 = (K > 0) ? (K - 1) : 0;
  int kp1 = (K < 127) ? (K + 1) : 127;
  int fA = half ? K : km1;
  int fB = half ? kp1 : K;
  const float4* eA = (const float4*)(env_ws + fA * 1024 + lane * 16);
  const float4* eB = (const float4*)(env_ws + fB * 1024 + lane * 16);
  float ev[16], sl[16];
  float basew = (half ? 0.5f : 128.5f) + (float)(sub * 16 + w * 8);
  #pragma unroll
  for (int q = 0; q < 4; ++q) {
    float4 a = eA[q], bb = eB[q];
    float d;
    d = (bb.x - a.x) * (1.0f / 256.0f); sl[q*4+0] = d; ev[q*4+0] = a.x + d * basew;
    d = (bb.y - a.y) * (1.0f / 256.0f); sl[q*4+1] = d; ev[q*4+1] = a.y + d * basew;
    d = (bb.z - a.z) * (1.0f / 256.0f); sl[q*4+2] = d; ev[q*4+2] = a.z + d * basew;
    d = (bb.w - a.w) * (1.0f / 256.0f); sl[q*4+3] = d; ev[q*4+3] = a.w + d * basew;
  }

  #pragma unroll
  for (int j = 0; j < 8; ++j) {
    float twoC = c1 + c1;
    float sm1 = 0.0f, sc = s1;
    float acc = ev[0] * sc; ev[0] += sl[0];
    #pragma unroll
    for (int i = 1; i < 16; ++i) {
      float sn = fmaf(twoC, sc, -sm1);
      sm1 = sc; sc = sn;
      acc = fmaf(ev[i], sn, acc);
      ev[i] += sl[i];
    }
    acc += __shfl_xor(acc, 32);
    acc += __shfl_xor(acc, 16);
    acc += __shfl_xor(acc, 8);
    acc += __shfl_xor(acc, 4);
    acc += __shfl_xor(acc, 2);
    acc += __shfl_xor(acc, 1);
    if (lane == 0) oscs[w * 8 + j] = acc;
    float tn = fmaf(s1, crot, c1 * srot);      // uses old s1,c1
    c1 = fmaf(c1, crot, -(s1 * srot));
    s1 = tn;
  }
  __syncthreads();

  // batch-mean of noise: 8 groups x 8 batches, 16 samples
  {
    int j = tid & 15, grp = tid >> 4;
    const float* src = ws2f + (size_t)(grp * 8) * NSAMP + s0 + j;
    float acc = 0.0f;
    #pragma unroll
    for (int bb = 0; bb < 8; ++bb) acc += src[(size_t)bb * NSAMP];
    nse[grp][j] = acc;
  }
  __syncthreads();

  if (tid < 16) {
    float nz = 0.0f;
    #pragma unroll
    for (int g = 0; g < 8; ++g) nz += nse[g][tid];
    out[s0 + tid] = oscs[tid] * (1.0f / 1024.0f) + nz * (1.0f / 64.0f);
  }
}

// ---------------------------------------------------------------------------
// fused pipeline: A |batchbar| B |batchbar| C |globalbar| D
// batch = wg & 63 -> all 32 WGs of a batch on XCD (b%8); batches pipeline
// independently through A/B/C (per-batch sync only); one global sync pre-D.
// ---------------------------------------------------------------------------
__global__ __launch_bounds__(128, 4) void kcoop(
    const float* __restrict__ noise_u, float2* __restrict__ A,
    float2* __restrict__ ws2, const float* __restrict__ packed,
    const float* __restrict__ gumbel, double* __restrict__ r64_ws,
    float* __restrict__ env_ws, float* __restrict__ out, unsigned* ctr) {
  __shared__ float2 zs[4 * ZROW];
  __shared__ float2 tws[64];
  int wg = blockIdx.x, tid = threadIdx.x;
  int b = wg & 63, t = wg >> 6;

  if (tid < 64) {
    float s, c;
    __sincosf(-(float)M_PI * (float)tid * (1.0f / 64.0f), &s, &c);
    tws[tid] = make_float2(c, s);
  }
  if (t == 0) k1_body(packed, gumbel, r64_ws, env_ws, b, tid);
  kf1_body(zs, tws, noise_u, A, b, t, tid);
  batchbar(ctr, 0, b);
  kmid_body(zs, tws, packed, A, b, t, tid);
  batchbar(ctr, 1, b);
  ki2_body(zs, tws, packed, A, ws2, b, t, tid);
  globalbar(ctr, 2, b);
  k3r_body(r64_ws, env_ws, (const float*)ws2, out, wg, tid);
}

// ---------------------------------------------------------------------------
extern "C" void kernel_launch(void* const* d_in, const int* in_sizes, int n_in,
                              void* d_out, int out_size, void* d_ws, size_t ws_size,
                              hipStream_t stream) {
  const float* packed  = (const float*)d_in[0];
  const float* gumbel  = (const float*)d_in[1];
  const float* noise_u = (const float*)d_in[2];
  float* out = (float*)d_out;

  // ws layout: [r64 8KB][env 512KB][A 8MB][ws2 8MB] ... [ctr @20MB, 64KB]
  char* wsc = (char*)d_ws;
  double*   r64_ws = (double*)wsc;
  float*    env_ws = (float*)(wsc + 8192);
  float2*   A      = (float2*)(wsc + 8192 + 524288);
  float2*   ws2    = (float2*)(wsc + 8192 + 524288 + (size_t)BATCH * MFFT * 8);
  unsigned* ctr    = (unsigned*)(wsc + (size_t)20 * 1024 * 1024);

  hipMemsetAsync(ctr, 0, 65536, stream);
  kcoop<<<NWG, 128, 0, stream>>>(noise_u, A, ws2, packed, gumbel,
                                 r64_ws, env_ws, out, ctr);
}

// Round 11
// 231.767 us; speedup vs baseline: 4.2839x; 3.0786x over previous
//
#include <hip/hip_runtime.h>
#include <math.h>

#define NSAMP   32768
#define NFRAMES 128
#define NHARM   16
#define BATCH   64
#define MFFT    16384          // complex FFT size (even/odd real pack), = 128*128
#define ZROW    137            // LDS row stride (float2) per 128-entry FFT row
#define NWG     2048           // 8 WG/CU x 256 CU -- co-residency by capacity

static __device__ __forceinline__ float clampf(float x, float lo, float hi) {
  return fminf(fmaxf(x, lo), hi);
}
static __device__ __forceinline__ int zp(int fft, int p) {        // LDS swizzle
  return fft * ZROW + p + (p >> 4);
}
static __device__ __forceinline__ int brev7(int n) {
  return (int)(__brev((unsigned)n) >> 25);
}
static __device__ __forceinline__ float2 cmulf(float c, float s, float2 v) {
  return make_float2(c * v.x - s * v.y, c * v.y + s * v.x);
}
static __device__ __forceinline__ float2 f2add(float2 a, float2 b) {
  return make_float2(a.x + b.x, a.y + b.y);
}
static __device__ __forceinline__ float2 f2sub(float2 a, float2 b) {
  return make_float2(a.x - b.x, a.y - b.y);
}

// ---------------------------------------------------------------------------
// Per-batch barrier (32 WGs). Counters on separate 128B lines, zeroed by
// hipMemsetAsync per call. KEY: spins and arrivals are RELAXED (no cache
// maintenance per poll -- agent scope still routes them to the coherent
// point); exactly ONE release fence before arrival and ONE acquire fence
// after release, executed by thread0 only. __syncthreads has already
// drained all waves' stores to L2 (compiler waitcnt before s_barrier).
// ---------------------------------------------------------------------------
static __device__ __forceinline__ void batchbar(unsigned* ctr, int p, int b) {
  __syncthreads();
  if (threadIdx.x == 0) {
    __threadfence();                       // release: flush dirty L2 -> LLC
    unsigned* a = ctr + (p * 64 + b) * 32;
    __hip_atomic_fetch_add(a, 1u, __ATOMIC_RELAXED, __HIP_MEMORY_SCOPE_AGENT);
    while (__hip_atomic_load(a, __ATOMIC_RELAXED, __HIP_MEMORY_SCOPE_AGENT) < 32u)
      __builtin_amdgcn_s_sleep(8);
    __threadfence();                       // acquire: invalidate L1/L2 once
  }
  __syncthreads();
}

// ---------------------------------------------------------------------------
// 4 FFTs of length 128 in LDS, 128 threads, radix-4 fused stage-pairs
// (3 radix-4 + 1 radix-2). DIT: bit-reversed input -> natural output.
// tws[j] = e^{-i pi j/64}; INV conjugates; w2b = (fwd) -i*w2a / (inv) +i*w2a.
// ---------------------------------------------------------------------------
template <bool INV>
static __device__ __forceinline__ void fft128_r4(float2* zs, const float2* tws, int tid) {
  int fft = tid >> 5, i = tid & 31;
  #pragma unroll
  for (int s = 0; s < 6; s += 2) {
    int half = 1 << s;
    int kk1 = i & (half - 1);
    int base = ((i & ~(half - 1)) << 2) | kk1;
    int p0 = zp(fft, base),            p1 = zp(fft, base + half);
    int p2 = zp(fft, base + 2 * half), p3 = zp(fft, base + 3 * half);
    float2 q0 = zs[p0], q1 = zs[p1], q2 = zs[p2], q3 = zs[p3];
    float2 t1 = tws[kk1 << (6 - s)], t2 = tws[kk1 << (5 - s)];
    float c1 = t1.x, s1 = INV ? -t1.y : t1.y;
    float c2 = t2.x, s2 = INV ? -t2.y : t2.y;
    float c2b = INV ? -s2 : s2, s2b = INV ? c2 : -c2;
    float2 t;
    t = cmulf(c1, s1, q1);   float2 A0 = f2add(q0, t), A1 = f2sub(q0, t);
    t = cmulf(c1, s1, q3);   float2 A2 = f2add(q2, t), A3 = f2sub(q2, t);
    t = cmulf(c2, s2, A2);   zs[p0] = f2add(A0, t); zs[p2] = f2sub(A0, t);
    t = cmulf(c2b, s2b, A3); zs[p1] = f2add(A1, t); zs[p3] = f2sub(A1, t);
    __syncthreads();
  }
  #pragma unroll
  for (int j = tid; j < 256; j += 128) {           // stage 6, radix-2
    int f = j >> 6, kk = j & 63;
    float2 w = tws[kk];
    float cc = w.x, ss = INV ? -w.y : w.y;
    int a0 = zp(f, kk), a1 = zp(f, kk + 64);
    float2 a = zs[a0], bv = zs[a1];
    float2 t = cmulf(cc, ss, bv);
    zs[a0] = f2add(a, t); zs[a1] = f2sub(a, t);
  }
  __syncthreads();
}

// Inverse as DIF: natural input -> bit-reversed output. Stage 6 first, then
// fused pairs (5,4),(3,2),(1,0). Twiddles conjugated; w2b = +i*w2a.
static __device__ __forceinline__ void fft128_r4_dif_inv(float2* zs, const float2* tws, int tid) {
  #pragma unroll
  for (int j = tid; j < 256; j += 128) {           // stage 6, radix-2 DIF
    int f = j >> 6, kk = j & 63;
    float2 w = tws[kk];
    float cc = w.x, ss = -w.y;
    int a0 = zp(f, kk), a1 = zp(f, kk + 64);
    float2 u = zs[a0], v = zs[a1];
    zs[a0] = f2add(u, v);
    zs[a1] = cmulf(cc, ss, f2sub(u, v));
  }
  __syncthreads();
  int fft = tid >> 5, i = tid & 31;
  #pragma unroll
  for (int s = 4; s >= 0; s -= 2) {
    int half = 1 << s;
    int kk1 = i & (half - 1);
    int base = ((i & ~(half - 1)) << 2) | kk1;
    int p0 = zp(fft, base),            p1 = zp(fft, base + half);
    int p2 = zp(fft, base + 2 * half), p3 = zp(fft, base + 3 * half);
    float2 q0 = zs[p0], q1 = zs[p1], q2 = zs[p2], q3 = zs[p3];
    float2 t1 = tws[kk1 << (6 - s)], t2 = tws[kk1 << (5 - s)];
    float c1 = t1.x, s1 = -t1.y;
    float c2 = t2.x, s2 = -t2.y;
    float c2b = -s2, s2b = c2;                  // +i * (c2, s2)
    float2 B0 = f2add(q0, q2);
    float2 B2 = cmulf(c2, s2, f2sub(q0, q2));
    float2 B1 = f2add(q1, q3);
    float2 B3 = cmulf(c2b, s2b, f2sub(q1, q3));
    zs[p0] = f2add(B0, B1);
    zs[p1] = cmulf(c1, s1, f2sub(B0, B1));
    zs[p2] = f2add(B2, B3);
    zs[p3] = cmulf(c1, s1, f2sub(B2, B3));
    __syncthreads();
  }
}

static __device__ __forceinline__ float h_filter(int f, const float* nf_s) {
  float coords = ((float)f + 0.5f) * (1.0f / 256.0f) - 0.5f;
  coords = clampf(coords, 0.0f, 63.0f);
  int i0 = (int)coords;
  int i1 = (i0 < 63) ? (i0 + 1) : 63;
  float w = coords - (float)i0;
  return nf_s[i0] * (1.0f - w) + nf_s[i1] * w;
}

static __device__ __forceinline__ float amp_lerp(int s, const float* amp_s) {
  float coords = ((float)s + 0.5f) * (1.0f / 256.0f) - 0.5f;
  coords = clampf(coords, 0.0f, 127.0f);
  int i0 = (int)coords;
  int i1 = (i0 < 127) ? (i0 + 1) : 127;
  float w = coords - (float)i0;
  float v = amp_s[i0] * (1.0f - w) + amp_s[i1] * w;
  return clampf(v, 0.0f, 1.0f);
}

// ---------------------------------------------------------------------------
// k1 body (t==0 WGs, phase A): gumbel argmax -> f0 -> radians (f64);
// 128-frame env scan. env layout: env_ws[frame*1024 + channel]
// ---------------------------------------------------------------------------
static __device__ void k1_body(
    const float* __restrict__ packed, const float* __restrict__ gumbel,
    double* __restrict__ r64_ws, float* __restrict__ env_ws, int b, int tid) {
  __shared__ double zv[128];
  __shared__ int    zi[128];
  __shared__ double f0_sh;
  const float* pk = packed + b * 480;

  double u = (double)gumbel[b * 128 + tid];
  double t = -log(u + 1e-10);
  double g = -log(t + 1e-10);
  zv[tid] = (double)pk[tid] + g;
  zi[tid] = tid;
  __syncthreads();
  for (int s = 64; s > 0; s >>= 1) {
    if (tid < s) {
      double a = zv[tid], c = zv[tid + s];
      int ia = zi[tid], ic = zi[tid + s];
      if (c > a || (c == a && ic < ia)) { zv[tid] = c; zi[tid] = ic; }
    }
    __syncthreads();
  }
  if (tid == 0) {
    int note = zi[0];
    double Fd  = 440.0 * exp2(((double)(note - 69)) / 12.0) / 11025.0;
    float  F32 = (float)Fd;                     // FREQS is f32 in the reference
    double f0  = (double)F32 * 11025.0;
    f0 = (40.0 / 11025.0) + f0 * (3000.0 / 11025.0 - 40.0 / 11025.0);
    f0_sh = f0;
  }
  __syncthreads();
  if (tid < NHARM) {
    int h = tid;
    int c = b * NHARM + h;
    const float PIF = 3.14159265358979323846f;  // float32(np.pi)
    double osc = f0_sh * (double)(h + 1);
    r64_ws[c] = (osc / 11025.0) * (double)PIF;
    float ha = pk[384 + h];
    float hd = 0.1f + pk[400 + h] * 0.9f;
    float cur = 0.0f;
    for (int tt = 0; tt < NFRAMES; ++tt) {
      float a = pk[256 + tt] * 2.0f - 1.0f;
      cur = clampf(cur + a * ha, 0.0f, 1.0f);
      env_ws[tt * 1024 + c] = cur;
      cur = cur * hd;
    }
  }
  __syncthreads();
}

// ---------------------------------------------------------------------------
// phase A: column FFTs (length 128 over n1) + W_M^{n2 k1} twiddle
// ---------------------------------------------------------------------------
static __device__ void kf1_body(
    float2* zs, const float2* tws, const float* __restrict__ noise_u,
    float2* __restrict__ A, int b, int tile, int tid) {
  const float2* nu2 = (const float2*)(noise_u + (size_t)b * NSAMP);
  #pragma unroll
  for (int it = 0; it < 4; ++it) {
    int e = it * 128 + tid;
    int n1 = e >> 2, n2l = e & 3;
    float2 xv = nu2[n1 * 128 + tile * 4 + n2l];
    zs[zp(n2l, brev7(n1))] = make_float2(xv.x * 2.0f - 1.0f, xv.y * 2.0f - 1.0f);
  }
  __syncthreads();
  fft128_r4<false>(zs, tws, tid);
  float2* Ab = A + (size_t)b * MFFT;
  #pragma unroll
  for (int it = 0; it < 4; ++it) {
    int e = it * 128 + tid;
    int k1 = e >> 2, n2l = e & 3;
    int n2 = tile * 4 + n2l;
    float2 v = zs[zp(n2l, k1)];
    float ang = -(2.0f * (float)M_PI / 16384.0f) * (float)(k1 * n2);
    float ss, cc; __sincosf(ang, &ss, &cc);
    Ab[k1 * 128 + n2] = make_float2(cc * v.x - ss * v.y, cc * v.y + ss * v.x);
  }
}

// ---------------------------------------------------------------------------
// phase B: fused row-FFT (fwd) -> Hermitian filter (LDS) -> row-IFFT (DIF)
//          -> conj twiddle. 4 rows = 2 pair-groups per WG.
// ---------------------------------------------------------------------------
static __device__ void kmid_body(
    float2* zs, const float2* tws, const float* __restrict__ packed,
    float2* __restrict__ A, int b, int t, int tid) {
  __shared__ float nf_s[64];
  __shared__ int   rowk1[4];
  if (tid >= 64 && tid < 128) nf_s[tid - 64] = packed[b * 480 + 416 + (tid - 64)];
  if (tid < 4) {
    int s = tid & 1;
    int m = t * 2 + s;
    rowk1[tid] = (tid < 2) ? m : ((m == 0) ? 64 : 128 - m);
  }
  __syncthreads();
  float2* Ab = A + (size_t)b * MFFT;

  #pragma unroll
  for (int it = 0; it < 4; ++it) {
    int e = it * 128 + tid;
    int r = e >> 7, n2 = e & 127;
    zs[zp(r, brev7(n2))] = Ab[rowk1[r] * 128 + n2];
  }
  __syncthreads();
  fft128_r4<false>(zs, tws, tid);   // zs[zp(r,k2)] = Z[rowk1[r] + 128*k2]

  const float hsc = 1.0f / 16384.0f;
  #pragma unroll
  for (int it = 0; it < 2; ++it) {
    int task = it * 128 + tid;      // 256 tasks: (local row r, k2 in 0..63)
    int r  = task >> 6;
    int k2 = task & 63;
    int k1 = rowk1[r];
    int f = k1 + (k2 << 7);
    if (f == 0) {                   // DC and f=8192 specials (WG t=0 only)
      float2 Z0 = zs[zp(0, 0)];
      float X0 = Z0.x + Z0.y;
      float Y0 = X0 * (h_filter(0, nf_s) * hsc);
      zs[zp(0, 0)] = make_float2(0.5f * Y0, 0.5f * Y0);   // H[M]=0 -> YM=0
      float Hm = h_filter(8192, nf_s) * hsc;
      float2 Zm = zs[zp(0, 64)];
      zs[zp(0, 64)] = make_float2(Zm.x * Hm, Zm.y * Hm);
    } else {
      int g = 16384 - f;
      int k1g = g & 127;
      int pr = (k1g == k1) ? r : ((r < 2) ? r + 2 : r - 2);
      int k2p = g >> 7;
      float2 Zf = zs[zp(r, k2)], Zg = zs[zp(pr, k2p)];
      float Ax = 0.5f * (Zf.x + Zg.x), Ay = 0.5f * (Zf.y - Zg.y);
      float Bx = 0.5f * (Zf.x - Zg.x), By = 0.5f * (Zf.y + Zg.y);
      float ang = (-(float)M_PI / (float)MFFT) * (float)f;
      float ss, cc; __sincosf(ang, &ss, &cc);
      float WBx = cc * Bx - ss * By, WBy = cc * By + ss * Bx;
      float Hf = h_filter(f, nf_s) * hsc;
      float Hg = h_filter(g, nf_s) * hsc;
      float Yfx = (Ax + WBy) * Hf, Yfy = (Ay - WBx) * Hf;
      float Ygx = (Ax - WBy) * Hg, Ygy = (-Ay - WBx) * Hg;
      float A2x = 0.5f * (Yfx + Ygx), A2y = 0.5f * (Yfy - Ygy);
      float B2x = 0.5f * (Yfx - Ygx), B2y = 0.5f * (Yfy + Ygy);
      float CBx = cc * B2x + ss * B2y;
      float CBy = cc * B2y - ss * B2x;
      zs[zp(r, k2)]   = make_float2(A2x - CBy, A2y + CBx);
      float DBx = cc * B2x + ss * B2y;
      float DBy = ss * B2x - cc * B2y;
      zs[zp(pr, k2p)] = make_float2(A2x - DBy, -A2y + DBx);
    }
  }
  __syncthreads();

  fft128_r4_dif_inv(zs, tws, tid);  // natural -> bitrev

  #pragma unroll
  for (int it = 0; it < 4; ++it) {
    int e = it * 128 + tid;
    int r = e >> 7, n2 = e & 127;
    int k1 = rowk1[r];
    float2 v = zs[zp(r, brev7(n2))];
    float ang = (2.0f * (float)M_PI / 16384.0f) * (float)(k1 * n2);
    float ss, cc; __sincosf(ang, &ss, &cc);
    Ab[k1 * 128 + n2] = make_float2(cc * v.x - ss * v.y, cc * v.y + ss * v.x);
  }
}

// ---------------------------------------------------------------------------
// phase C: column inverse FFTs (over k1) + amp*clip -> ws2
// ---------------------------------------------------------------------------
static __device__ void ki2_body(
    float2* zs, const float2* tws, const float* __restrict__ packed,
    const float2* __restrict__ A, float2* __restrict__ ws2, int b, int tile, int tid) {
  __shared__ float amp_s[128];
  amp_s[tid] = packed[b * 480 + 256 + tid] * 2.0f - 1.0f;
  const float2* Ab = A + (size_t)b * MFFT;
  #pragma unroll
  for (int it = 0; it < 4; ++it) {
    int e = it * 128 + tid;
    int k1 = e >> 2, n2l = e & 3;
    zs[zp(n2l, brev7(k1))] = Ab[k1 * 128 + tile * 4 + n2l];
  }
  __syncthreads();
  fft128_r4<true>(zs, tws, tid);
  float2* W2 = ws2 + (size_t)b * MFFT;
  #pragma unroll
  for (int it = 0; it < 4; ++it) {
    int e = it * 128 + tid;
    int n1 = e >> 2, n2l = e & 3;
    int n2 = tile * 4 + n2l;
    int n = n1 * 128 + n2;
    float2 v = zs[zp(n2l, n1)];
    v.x *= amp_lerp(2 * n,     amp_s);
    v.y *= amp_lerp(2 * n + 1, amp_s);
    W2[n] = v;
  }
}

// ---------------------------------------------------------------------------
// kernel 1: A |batchbar| B |batchbar| C   (per-batch sync only)
// batch = wg & 63 -> all 32 WGs of a batch tend to one XCD (locality only).
// ---------------------------------------------------------------------------
__global__ __launch_bounds__(128, 4) void kabc(
    const float* __restrict__ noise_u, float2* __restrict__ A,
    float2* __restrict__ ws2, const float* __restrict__ packed,
    const float* __restrict__ gumbel, double* __restrict__ r64_ws,
    float* __restrict__ env_ws, unsigned* ctr) {
  __shared__ float2 zs[4 * ZROW];
  __shared__ float2 tws[64];
  int wg = blockIdx.x, tid = threadIdx.x;
  int b = wg & 63, t = wg >> 6;

  if (tid < 64) {
    float s, c;
    __sincosf(-(float)M_PI * (float)tid * (1.0f / 64.0f), &s, &c);
    tws[tid] = make_float2(c, s);
  }
  if (t == 0) k1_body(packed, gumbel, r64_ws, env_ws, b, tid);
  kf1_body(zs, tws, noise_u, A, b, t, tid);
  batchbar(ctr, 0, b);
  kmid_body(zs, tws, packed, A, b, t, tid);
  batchbar(ctr, 1, b);
  ki2_body(zs, tws, packed, A, ws2, b, t, tid);
}

// ---------------------------------------------------------------------------
// kernel 2 (phase D): oscillator bank (Chebyshev harmonic recurrence) +
// batch-mean of noise. wg = chunk*8 + sub; WG covers 16 samples.
// ---------------------------------------------------------------------------
__global__ __launch_bounds__(128) void kd(
    const double* __restrict__ r64_ws, const float* __restrict__ env_ws,
    const float* __restrict__ ws2f, float* __restrict__ out) {
  __shared__ float nse[8][16];
  __shared__ float oscs[16];
  const double TWO_PI     = 6.283185307179586476925286766559;
  const double INV_TWO_PI = 0.15915494309189533576888376337251;
  int wg = blockIdx.x, tid = threadIdx.x;
  int lane = tid & 63;               // batch
  int w = tid >> 6;                  // wave: 8 samples each
  int chunk = wg >> 3, sub = wg & 7;
  int s0 = chunk * 128 + sub * 16;
  int K = chunk >> 1, half = chunk & 1;

  double r0 = r64_ws[lane * 16];     // fundamental step angle (f64)
  double rr = r0 - rint(r0 * INV_TWO_PI) * TWO_PI;
  double x0 = (double)(s0 + w * 8 + 1) * r0;
  double ph = x0 - rint(x0 * INV_TWO_PI) * TWO_PI;
  float s1, c1, srot, crot;
  __sincosf((float)ph, &s1, &c1);
  __sincosf((float)rr, &srot, &crot);

  int km1 = (K > 0) ? (K - 1) : 0;
  int kp1 = (K < 127) ? (K + 1) : 127;
  int fA = half ? K : km1;
  int fB = half ? kp1 : K;
  const float4* eA = (const float4*)(env_ws + fA * 1024 + lane * 16);
  const float4* eB = (const float4*)(env_ws + fB * 1024 + lane * 16);
  float ev[16], sl[16];
  float basew = (half ? 0.5f : 128.5f) + (float)(sub * 16 + w * 8);
  #pragma unroll
  for (int q = 0; q < 4; ++q) {
    float4 a = eA[q], bb = eB[q];
    float d;
    d = (bb.x - a.x) * (1.0f / 256.0f); sl[q*4+0] = d; ev[q*4+0] = a.x + d * basew;
    d = (bb.y - a.y) * (1.0f / 256.0f); sl[q*4+1] = d; ev[q*4+1] = a.y + d * basew;
    d = (bb.z - a.z) * (1.0f / 256.0f); sl[q*4+2] = d; ev[q*4+2] = a.z + d * basew;
    d = (bb.w - a.w) * (1.0f / 256.0f); sl[q*4+3] = d; ev[q*4+3] = a.w + d * basew;
  }

  #pragma unroll
  for (int j = 0; j < 8; ++j) {
    float twoC = c1 + c1;
    float sm1 = 0.0f, sc = s1;
    float acc = ev[0] * sc; ev[0] += sl[0];
    #pragma unroll
    for (int i = 1; i < 16; ++i) {
      float sn = fmaf(twoC, sc, -sm1);
      sm1 = sc; sc = sn;
      acc = fmaf(ev[i], sn, acc);
      ev[i] += sl[i];
    }
    acc += __shfl_xor(acc, 32);
    acc += __shfl_xor(acc, 16);
    acc += __shfl_xor(acc, 8);
    acc += __shfl_xor(acc, 4);
    acc += __shfl_xor(acc, 2);
    acc += __shfl_xor(acc, 1);
    if (lane == 0) oscs[w * 8 + j] = acc;
    float tn = fmaf(s1, crot, c1 * srot);      // uses old s1,c1
    c1 = fmaf(c1, crot, -(s1 * srot));
    s1 = tn;
  }
  __syncthreads();

  // batch-mean of noise: 8 groups x 8 batches, 16 samples
  {
    int j = tid & 15, grp = tid >> 4;
    const float* src = ws2f + (size_t)(grp * 8) * NSAMP + s0 + j;
    float acc = 0.0f;
    #pragma unroll
    for (int bb = 0; bb < 8; ++bb) acc += src[(size_t)bb * NSAMP];
    nse[grp][j] = acc;
  }
  __syncthreads();

  if (tid < 16) {
    float nz = 0.0f;
    #pragma unroll
    for (int g = 0; g < 8; ++g) nz += nse[g][tid];
    out[s0 + tid] = oscs[tid] * (1.0f / 1024.0f) + nz * (1.0f / 64.0f);
  }
}

// ---------------------------------------------------------------------------
extern "C" void kernel_launch(void* const* d_in, const int* in_sizes, int n_in,
                              void* d_out, int out_size, void* d_ws, size_t ws_size,
                              hipStream_t stream) {
  const float* packed  = (const float*)d_in[0];
  const float* gumbel  = (const float*)d_in[1];
  const float* noise_u = (const float*)d_in[2];
  float* out = (float*)d_out;

  // ws layout: [r64 8KB][env 512KB][A 8MB][ws2 8MB] ... [ctr @20MB, 64KB]
  char* wsc = (char*)d_ws;
  double*   r64_ws = (double*)wsc;
  float*    env_ws = (float*)(wsc + 8192);
  float2*   A      = (float2*)(wsc + 8192 + 524288);
  float2*   ws2    = (float2*)(wsc + 8192 + 524288 + (size_t)BATCH * MFFT * 8);
  unsigned* ctr    = (unsigned*)(wsc + (size_t)20 * 1024 * 1024);

  hipMemsetAsync(ctr, 0, 65536, stream);
  kabc<<<NWG, 128, 0, stream>>>(noise_u, A, ws2, packed, gumbel,
                                r64_ws, env_ws, ctr);
  kd  <<<NWG, 128, 0, stream>>>(r64_ws, env_ws, (const float*)ws2, out);
}

// Round 12
// 47.377 us; speedup vs baseline: 20.9567x; 4.8920x over previous
//
#include <hip/hip_runtime.h>
#include <math.h>

#define NSAMP   32768
#define NFRAMES 128
#define NHARM   16
#define BATCH   64
#define MFFT    16384          // complex FFT size (even/odd real pack), = 128*128
#define ZROW    137            // LDS row stride (float2) per 128-entry FFT row
#define NWG     2048           // 8 WG/CU x 256 CU -- co-residency by capacity

static __device__ __forceinline__ float clampf(float x, float lo, float hi) {
  return fminf(fmaxf(x, lo), hi);
}
static __device__ __forceinline__ int zp(int fft, int p) {        // LDS swizzle
  return fft * ZROW + p + (p >> 4);
}
static __device__ __forceinline__ int brev7(int n) {
  return (int)(__brev((unsigned)n) >> 25);
}
static __device__ __forceinline__ float2 cmulf(float c, float s, float2 v) {
  return make_float2(c * v.x - s * v.y, c * v.y + s * v.x);
}
static __device__ __forceinline__ float2 f2add(float2 a, float2 b) {
  return make_float2(a.x + b.x, a.y + b.y);
}
static __device__ __forceinline__ float2 f2sub(float2 a, float2 b) {
  return make_float2(a.x - b.x, a.y - b.y);
}

// ---------------------------------------------------------------------------
// LLC-direct (agent-coherent) 8B accessors for cross-WG buffers: compile to
// global_load/store_dwordx2 with agent coherence bits -> served at the device
// coherence point. No stale per-XCD L2 copies, no cache-maintenance needed.
// ---------------------------------------------------------------------------
static __device__ __forceinline__ float2 llc_load(const float2* p) {
  unsigned long long v = __hip_atomic_load((const unsigned long long*)p,
                                           __ATOMIC_RELAXED, __HIP_MEMORY_SCOPE_AGENT);
  union { unsigned long long u; float2 f; } cv; cv.u = v; return cv.f;
}
static __device__ __forceinline__ void llc_store(float2* p, float2 x) {
  union { unsigned long long u; float2 f; } cv; cv.f = x;
  __hip_atomic_store((unsigned long long*)p, cv.u,
                     __ATOMIC_RELAXED, __HIP_MEMORY_SCOPE_AGENT);
}

// ---------------------------------------------------------------------------
// Per-batch barrier (32 WGs), fence-free: all cross-WG data moves via llc_*
// (already at the coherence point), and __syncthreads drains vmcnt(0) before
// thread0's arrival add, so arrival implies data visibility. Counters on
// separate 128B lines, zeroed by hipMemsetAsync per call.
// ---------------------------------------------------------------------------
static __device__ __forceinline__ void batchbar(unsigned* ctr, int p, int b) {
  __syncthreads();
  if (threadIdx.x == 0) {
    unsigned* a = ctr + (p * 64 + b) * 32;
    __hip_atomic_fetch_add(a, 1u, __ATOMIC_RELAXED, __HIP_MEMORY_SCOPE_AGENT);
    while (__hip_atomic_load(a, __ATOMIC_RELAXED, __HIP_MEMORY_SCOPE_AGENT) < 32u)
      __builtin_amdgcn_s_sleep(2);
  }
  __syncthreads();
}

// ---------------------------------------------------------------------------
// 4 FFTs of length 128 in LDS, 128 threads, radix-4 fused stage-pairs
// (3 radix-4 + 1 radix-2). DIT: bit-reversed input -> natural output.
// tws[j] = e^{-i pi j/64}; INV conjugates; w2b = (fwd) -i*w2a / (inv) +i*w2a.
// ---------------------------------------------------------------------------
template <bool INV>
static __device__ __forceinline__ void fft128_r4(float2* zs, const float2* tws, int tid) {
  int fft = tid >> 5, i = tid & 31;
  #pragma unroll
  for (int s = 0; s < 6; s += 2) {
    int half = 1 << s;
    int kk1 = i & (half - 1);
    int base = ((i & ~(half - 1)) << 2) | kk1;
    int p0 = zp(fft, base),            p1 = zp(fft, base + half);
    int p2 = zp(fft, base + 2 * half), p3 = zp(fft, base + 3 * half);
    float2 q0 = zs[p0], q1 = zs[p1], q2 = zs[p2], q3 = zs[p3];
    float2 t1 = tws[kk1 << (6 - s)], t2 = tws[kk1 << (5 - s)];
    float c1 = t1.x, s1 = INV ? -t1.y : t1.y;
    float c2 = t2.x, s2 = INV ? -t2.y : t2.y;
    float c2b = INV ? -s2 : s2, s2b = INV ? c2 : -c2;
    float2 t;
    t = cmulf(c1, s1, q1);   float2 A0 = f2add(q0, t), A1 = f2sub(q0, t);
    t = cmulf(c1, s1, q3);   float2 A2 = f2add(q2, t), A3 = f2sub(q2, t);
    t = cmulf(c2, s2, A2);   zs[p0] = f2add(A0, t); zs[p2] = f2sub(A0, t);
    t = cmulf(c2b, s2b, A3); zs[p1] = f2add(A1, t); zs[p3] = f2sub(A1, t);
    __syncthreads();
  }
  #pragma unroll
  for (int j = tid; j < 256; j += 128) {           // stage 6, radix-2
    int f = j >> 6, kk = j & 63;
    float2 w = tws[kk];
    float cc = w.x, ss = INV ? -w.y : w.y;
    int a0 = zp(f, kk), a1 = zp(f, kk + 64);
    float2 a = zs[a0], bv = zs[a1];
    float2 t = cmulf(cc, ss, bv);
    zs[a0] = f2add(a, t); zs[a1] = f2sub(a, t);
  }
  __syncthreads();
}

// Inverse as DIF: natural input -> bit-reversed output. Stage 6 first, then
// fused pairs (5,4),(3,2),(1,0). Twiddles conjugated; w2b = +i*w2a.
static __device__ __forceinline__ void fft128_r4_dif_inv(float2* zs, const float2* tws, int tid) {
  #pragma unroll
  for (int j = tid; j < 256; j += 128) {           // stage 6, radix-2 DIF
    int f = j >> 6, kk = j & 63;
    float2 w = tws[kk];
    float cc = w.x, ss = -w.y;
    int a0 = zp(f, kk), a1 = zp(f, kk + 64);
    float2 u = zs[a0], v = zs[a1];
    zs[a0] = f2add(u, v);
    zs[a1] = cmulf(cc, ss, f2sub(u, v));
  }
  __syncthreads();
  int fft = tid >> 5, i = tid & 31;
  #pragma unroll
  for (int s = 4; s >= 0; s -= 2) {
    int half = 1 << s;
    int kk1 = i & (half - 1);
    int base = ((i & ~(half - 1)) << 2) | kk1;
    int p0 = zp(fft, base),            p1 = zp(fft, base + half);
    int p2 = zp(fft, base + 2 * half), p3 = zp(fft, base + 3 * half);
    float2 q0 = zs[p0], q1 = zs[p1], q2 = zs[p2], q3 = zs[p3];
    float2 t1 = tws[kk1 << (6 - s)], t2 = tws[kk1 << (5 - s)];
    float c1 = t1.x, s1 = -t1.y;
    float c2 = t2.x, s2 = -t2.y;
    float c2b = -s2, s2b = c2;                  // +i * (c2, s2)
    float2 B0 = f2add(q0, q2);
    float2 B2 = cmulf(c2, s2, f2sub(q0, q2));
    float2 B1 = f2add(q1, q3);
    float2 B3 = cmulf(c2b, s2b, f2sub(q1, q3));
    zs[p0] = f2add(B0, B1);
    zs[p1] = cmulf(c1, s1, f2sub(B0, B1));
    zs[p2] = f2add(B2, B3);
    zs[p3] = cmulf(c1, s1, f2sub(B2, B3));
    __syncthreads();
  }
}

static __device__ __forceinline__ float h_filter(int f, const float* nf_s) {
  float coords = ((float)f + 0.5f) * (1.0f / 256.0f) - 0.5f;
  coords = clampf(coords, 0.0f, 63.0f);
  int i0 = (int)coords;
  int i1 = (i0 < 63) ? (i0 + 1) : 63;
  float w = coords - (float)i0;
  return nf_s[i0] * (1.0f - w) + nf_s[i1] * w;
}

static __device__ __forceinline__ float amp_lerp(int s, const float* amp_s) {
  float coords = ((float)s + 0.5f) * (1.0f / 256.0f) - 0.5f;
  coords = clampf(coords, 0.0f, 127.0f);
  int i0 = (int)coords;
  int i1 = (i0 < 127) ? (i0 + 1) : 127;
  float w = coords - (float)i0;
  float v = amp_s[i0] * (1.0f - w) + amp_s[i1] * w;
  return clampf(v, 0.0f, 1.0f);
}

// ---------------------------------------------------------------------------
// k1 body (t==0 WGs, phase A): gumbel argmax -> f0 -> radians (f64);
// 128-frame env scan. env layout: env_ws[frame*1024 + channel]
// (r64/env consumed only by kd, across the kernel boundary -> plain stores)
// ---------------------------------------------------------------------------
static __device__ void k1_body(
    const float* __restrict__ packed, const float* __restrict__ gumbel,
    double* __restrict__ r64_ws, float* __restrict__ env_ws, int b, int tid) {
  __shared__ double zv[128];
  __shared__ int    zi[128];
  __shared__ double f0_sh;
  const float* pk = packed + b * 480;

  double u = (double)gumbel[b * 128 + tid];
  double t = -log(u + 1e-10);
  double g = -log(t + 1e-10);
  zv[tid] = (double)pk[tid] + g;
  zi[tid] = tid;
  __syncthreads();
  for (int s = 64; s > 0; s >>= 1) {
    if (tid < s) {
      double a = zv[tid], c = zv[tid + s];
      int ia = zi[tid], ic = zi[tid + s];
      if (c > a || (c == a && ic < ia)) { zv[tid] = c; zi[tid] = ic; }
    }
    __syncthreads();
  }
  if (tid == 0) {
    int note = zi[0];
    double Fd  = 440.0 * exp2(((double)(note - 69)) / 12.0) / 11025.0;
    float  F32 = (float)Fd;                     // FREQS is f32 in the reference
    double f0  = (double)F32 * 11025.0;
    f0 = (40.0 / 11025.0) + f0 * (3000.0 / 11025.0 - 40.0 / 11025.0);
    f0_sh = f0;
  }
  __syncthreads();
  if (tid < NHARM) {
    int h = tid;
    int c = b * NHARM + h;
    const float PIF = 3.14159265358979323846f;  // float32(np.pi)
    double osc = f0_sh * (double)(h + 1);
    r64_ws[c] = (osc / 11025.0) * (double)PIF;
    float ha = pk[384 + h];
    float hd = 0.1f + pk[400 + h] * 0.9f;
    float cur = 0.0f;
    for (int tt = 0; tt < NFRAMES; ++tt) {
      float a = pk[256 + tt] * 2.0f - 1.0f;
      cur = clampf(cur + a * ha, 0.0f, 1.0f);
      env_ws[tt * 1024 + c] = cur;
      cur = cur * hd;
    }
  }
  __syncthreads();
}

// ---------------------------------------------------------------------------
// phase A: column FFTs (length 128 over n1) + W_M^{n2 k1} twiddle
// ---------------------------------------------------------------------------
static __device__ void kf1_body(
    float2* zs, const float2* tws, const float* __restrict__ noise_u,
    float2* __restrict__ A, int b, int tile, int tid) {
  const float2* nu2 = (const float2*)(noise_u + (size_t)b * NSAMP);
  #pragma unroll
  for (int it = 0; it < 4; ++it) {
    int e = it * 128 + tid;
    int n1 = e >> 2, n2l = e & 3;
    float2 xv = nu2[n1 * 128 + tile * 4 + n2l];
    zs[zp(n2l, brev7(n1))] = make_float2(xv.x * 2.0f - 1.0f, xv.y * 2.0f - 1.0f);
  }
  __syncthreads();
  fft128_r4<false>(zs, tws, tid);
  float2* Ab = A + (size_t)b * MFFT;
  #pragma unroll
  for (int it = 0; it < 4; ++it) {
    int e = it * 128 + tid;
    int k1 = e >> 2, n2l = e & 3;
    int n2 = tile * 4 + n2l;
    float2 v = zs[zp(n2l, k1)];
    float ang = -(2.0f * (float)M_PI / 16384.0f) * (float)(k1 * n2);
    float ss, cc; __sincosf(ang, &ss, &cc);
    llc_store(&Ab[k1 * 128 + n2],
              make_float2(cc * v.x - ss * v.y, cc * v.y + ss * v.x));
  }
}

// ---------------------------------------------------------------------------
// phase B: fused row-FFT (fwd) -> Hermitian filter (LDS) -> row-IFFT (DIF)
//          -> conj twiddle. 4 rows = 2 pair-groups per WG.
// ---------------------------------------------------------------------------
static __device__ void kmid_body(
    float2* zs, const float2* tws, const float* __restrict__ packed,
    float2* __restrict__ A, int b, int t, int tid) {
  __shared__ float nf_s[64];
  __shared__ int   rowk1[4];
  if (tid >= 64 && tid < 128) nf_s[tid - 64] = packed[b * 480 + 416 + (tid - 64)];
  if (tid < 4) {
    int s = tid & 1;
    int m = t * 2 + s;
    rowk1[tid] = (tid < 2) ? m : ((m == 0) ? 64 : 128 - m);
  }
  __syncthreads();
  float2* Ab = A + (size_t)b * MFFT;

  #pragma unroll
  for (int it = 0; it < 4; ++it) {
    int e = it * 128 + tid;
    int r = e >> 7, n2 = e & 127;
    zs[zp(r, brev7(n2))] = llc_load(&Ab[rowk1[r] * 128 + n2]);
  }
  __syncthreads();
  fft128_r4<false>(zs, tws, tid);   // zs[zp(r,k2)] = Z[rowk1[r] + 128*k2]

  const float hsc = 1.0f / 16384.0f;
  #pragma unroll
  for (int it = 0; it < 2; ++it) {
    int task = it * 128 + tid;      // 256 tasks: (local row r, k2 in 0..63)
    int r  = task >> 6;
    int k2 = task & 63;
    int k1 = rowk1[r];
    int f = k1 + (k2 << 7);
    if (f == 0) {                   // DC and f=8192 specials (WG t=0 only)
      float2 Z0 = zs[zp(0, 0)];
      float X0 = Z0.x + Z0.y;
      float Y0 = X0 * (h_filter(0, nf_s) * hsc);
      zs[zp(0, 0)] = make_float2(0.5f * Y0, 0.5f * Y0);   // H[M]=0 -> YM=0
      float Hm = h_filter(8192, nf_s) * hsc;
      float2 Zm = zs[zp(0, 64)];
      zs[zp(0, 64)] = make_float2(Zm.x * Hm, Zm.y * Hm);
    } else {
      int g = 16384 - f;
      int k1g = g & 127;
      int pr = (k1g == k1) ? r : ((r < 2) ? r + 2 : r - 2);
      int k2p = g >> 7;
      float2 Zf = zs[zp(r, k2)], Zg = zs[zp(pr, k2p)];
      float Ax = 0.5f * (Zf.x + Zg.x), Ay = 0.5f * (Zf.y - Zg.y);
      float Bx = 0.5f * (Zf.x - Zg.x), By = 0.5f * (Zf.y + Zg.y);
      float ang = (-(float)M_PI / (float)MFFT) * (float)f;
      float ss, cc; __sincosf(ang, &ss, &cc);
      float WBx = cc * Bx - ss * By, WBy = cc * By + ss * Bx;
      float Hf = h_filter(f, nf_s) * hsc;
      float Hg = h_filter(g, nf_s) * hsc;
      float Yfx = (Ax + WBy) * Hf, Yfy = (Ay - WBx) * Hf;
      float Ygx = (Ax - WBy) * Hg, Ygy = (-Ay - WBx) * Hg;
      float A2x = 0.5f * (Yfx + Ygx), A2y = 0.5f * (Yfy - Ygy);
      float B2x = 0.5f * (Yfx - Ygx), B2y = 0.5f * (Yfy + Ygy);
      float CBx = cc * B2x + ss * B2y;
      float CBy = cc * B2y - ss * B2x;
      zs[zp(r, k2)]   = make_float2(A2x - CBy, A2y + CBx);
      float DBx = cc * B2x + ss * B2y;
      float DBy = ss * B2x - cc * B2y;
      zs[zp(pr, k2p)] = make_float2(A2x - DBy, -A2y + DBx);
    }
  }
  __syncthreads();

  fft128_r4_dif_inv(zs, tws, tid);  // natural -> bitrev

  #pragma unroll
  for (int it = 0; it < 4; ++it) {
    int e = it * 128 + tid;
    int r = e >> 7, n2 = e & 127;
    int k1 = rowk1[r];
    float2 v = zs[zp(r, brev7(n2))];
    float ang = (2.0f * (float)M_PI / 16384.0f) * (float)(k1 * n2);
    float ss, cc; __sincosf(ang, &ss, &cc);
    llc_store(&Ab[k1 * 128 + n2],
              make_float2(cc * v.x - ss * v.y, cc * v.y + ss * v.x));
  }
}

// ---------------------------------------------------------------------------
// phase C: column inverse FFTs (over k1) + amp*clip -> ws2 (plain stores;
// consumed by kd across the kernel boundary)
// ---------------------------------------------------------------------------
static __device__ void ki2_body(
    float2* zs, const float2* tws, const float* __restrict__ packed,
    const float2* __restrict__ A, float2* __restrict__ ws2, int b, int tile, int tid) {
  __shared__ float amp_s[128];
  amp_s[tid] = packed[b * 480 + 256 + tid] * 2.0f - 1.0f;
  const float2* Ab = A + (size_t)b * MFFT;
  #pragma unroll
  for (int it = 0; it < 4; ++it) {
    int e = it * 128 + tid;
    int k1 = e >> 2, n2l = e & 3;
    zs[zp(n2l, brev7(k1))] = llc_load(&Ab[k1 * 128 + tile * 4 + n2l]);
  }
  __syncthreads();
  fft128_r4<true>(zs, tws, tid);
  float2* W2 = ws2 + (size_t)b * MFFT;
  #pragma unroll
  for (int it = 0; it < 4; ++it) {
    int e = it * 128 + tid;
    int n1 = e >> 2, n2l = e & 3;
    int n2 = tile * 4 + n2l;
    int n = n1 * 128 + n2;
    float2 v = zs[zp(n2l, n1)];
    v.x *= amp_lerp(2 * n,     amp_s);
    v.y *= amp_lerp(2 * n + 1, amp_s);
    W2[n] = v;
  }
}

// ---------------------------------------------------------------------------
// kernel 1: A |batchbar| B |batchbar| C   (per-batch sync only)
// batch = wg & 63 -> all 32 WGs of a batch tend to one XCD (locality only;
// correctness does not depend on it -- llc_* ops are agent-coherent).
// ---------------------------------------------------------------------------
__global__ __launch_bounds__(128, 4) void kabc(
    const float* __restrict__ noise_u, float2* __restrict__ A,
    float2* __restrict__ ws2, const float* __restrict__ packed,
    const float* __restrict__ gumbel, double* __restrict__ r64_ws,
    float* __restrict__ env_ws, unsigned* ctr) {
  __shared__ float2 zs[4 * ZROW];
  __shared__ float2 tws[64];
  int wg = blockIdx.x, tid = threadIdx.x;
  int b = wg & 63, t = wg >> 6;

  if (tid < 64) {
    float s, c;
    __sincosf(-(float)M_PI * (float)tid * (1.0f / 64.0f), &s, &c);
    tws[tid] = make_float2(c, s);
  }
  if (t == 0) k1_body(packed, gumbel, r64_ws, env_ws, b, tid);
  kf1_body(zs, tws, noise_u, A, b, t, tid);
  batchbar(ctr, 0, b);
  kmid_body(zs, tws, packed, A, b, t, tid);
  batchbar(ctr, 1, b);
  ki2_body(zs, tws, packed, A, ws2, b, t, tid);
}

// ---------------------------------------------------------------------------
// kernel 2 (phase D): oscillator bank (Chebyshev harmonic recurrence) +
// batch-mean of noise. wg = chunk*8 + sub; WG covers 16 samples.
// ---------------------------------------------------------------------------
__global__ __launch_bounds__(128) void kd(
    const double* __restrict__ r64_ws, const float* __restrict__ env_ws,
    const float* __restrict__ ws2f, float* __restrict__ out) {
  __shared__ float nse[8][16];
  __shared__ float oscs[16];
  const double TWO_PI     = 6.283185307179586476925286766559;
  const double INV_TWO_PI = 0.15915494309189533576888376337251;
  int wg = blockIdx.x, tid = threadIdx.x;
  int lane = tid & 63;               // batch
  int w = tid >> 6;                  // wave: 8 samples each
  int chunk = wg >> 3, sub = wg & 7;
  int s0 = chunk * 128 + sub * 16;
  int K = chunk >> 1, half = chunk & 1;

  double r0 = r64_ws[lane * 16];     // fundamental step angle (f64)
  double rr = r0 - rint(r0 * INV_TWO_PI) * TWO_PI;
  double x0 = (double)(s0 + w * 8 + 1) * r0;
  double ph = x0 - rint(x0 * INV_TWO_PI) * TWO_PI;
  float s1, c1, srot, crot;
  __sincosf((float)ph, &s1, &c1);
  __sincosf((float)rr, &srot, &crot);

  int km1 = (K > 0) ? (K - 1) : 0;
  int kp1 = (K < 127) ? (K + 1) : 127;
  int fA = half ? K : km1;
  int fB = half ? kp1 : K;
  const float4* eA = (const float4*)(env_ws + fA * 1024 + lane * 16);
  const float4* eB = (const float4*)(env_ws + fB * 1024 + lane * 16);
  float ev[16], sl[16];
  float basew = (half ? 0.5f : 128.5f) + (float)(sub * 16 + w * 8);
  #pragma unroll
  for (int q = 0; q < 4; ++q) {
    float4 a = eA[q], bb = eB[q];
    float d;
    d = (bb.x - a.x) * (1.0f / 256.0f); sl[q*4+0] = d; ev[q*4+0] = a.x + d * basew;
    d = (bb.y - a.y) * (1.0f / 256.0f); sl[q*4+1] = d; ev[q*4+1] = a.y + d * basew;
    d = (bb.z - a.z) * (1.0f / 256.0f); sl[q*4+2] = d; ev[q*4+2] = a.z + d * basew;
    d = (bb.w - a.w) * (1.0f / 256.0f); sl[q*4+3] = d; ev[q*4+3] = a.w + d * basew;
  }

  #pragma unroll
  for (int j = 0; j < 8; ++j) {
    float twoC = c1 + c1;
    float sm1 = 0.0f, sc = s1;
    float acc = ev[0] * sc; ev[0] += sl[0];
    #pragma unroll
    for (int i = 1; i < 16; ++i) {
      float sn = fmaf(twoC, sc, -sm1);
      sm1 = sc; sc = sn;
      acc = fmaf(ev[i], sn, acc);
      ev[i] += sl[i];
    }
    acc += __shfl_xor(acc, 32);
    acc += __shfl_xor(acc, 16);
    acc += __shfl_xor(acc, 8);
    acc += __shfl_xor(acc, 4);
    acc += __shfl_xor(acc, 2);
    acc += __shfl_xor(acc, 1);
    if (lane == 0) oscs[w * 8 + j] = acc;
    float tn = fmaf(s1, crot, c1 * srot);      // uses old s1,c1
    c1 = fmaf(c1, crot, -(s1 * srot));
    s1 = tn;
  }
  __syncthreads();

  // batch-mean of noise: 8 groups x 8 batches, 16 samples
  {
    int j = tid & 15, grp = tid >> 4;
    const float* src = ws2f + (size_t)(grp * 8) * NSAMP + s0 + j;
    float acc = 0.0f;
    #pragma unroll
    for (int bb = 0; bb < 8; ++bb) acc += src[(size_t)bb * NSAMP];
    nse[grp][j] = acc;
  }
  __syncthreads();

  if (tid < 16) {
    float nz = 0.0f;
    #pragma unroll
    for (int g = 0; g < 8; ++g) nz += nse[g][tid];
    out[s0 + tid] = oscs[tid] * (1.0f / 1024.0f) + nz * (1.0f / 64.0f);
  }
}

// ---------------------------------------------------------------------------
extern "C" void kernel_launch(void* const* d_in, const int* in_sizes, int n_in,
                              void* d_out, int out_size, void* d_ws, size_t ws_size,
                              hipStream_t stream) {
  const float* packed  = (const float*)d_in[0];
  const float* gumbel  = (const float*)d_in[1];
  const float* noise_u = (const float*)d_in[2];
  float* out = (float*)d_out;

  // ws layout: [r64 8KB][env 512KB][A 8MB][ws2 8MB] ... [ctr @20MB, 64KB]
  char* wsc = (char*)d_ws;
  double*   r64_ws = (double*)wsc;
  float*    env_ws = (float*)(wsc + 8192);
  float2*   A      = (float2*)(wsc + 8192 + 524288);
  float2*   ws2    = (float2*)(wsc + 8192 + 524288 + (size_t)BATCH * MFFT * 8);
  unsigned* ctr    = (unsigned*)(wsc + (size_t)20 * 1024 * 1024);

  hipMemsetAsync(ctr, 0, 65536, stream);
  kabc<<<NWG, 128, 0, stream>>>(noise_u, A, ws2, packed, gumbel,
                                r64_ws, env_ws, ctr);
  kd  <<<NWG, 128, 0, stream>>>(r64_ws, env_ws, (const float*)ws2, out);
}